// Round 2
// baseline (465.662 us; speedup 1.0000x reference)
//
#include <hip/hip_runtime.h>
#include <math.h>

#define T_TOKENS 2048
#define DMODEL   1024
#define HID      4096
#define NEXP     8
#define MAX_TILES 32

typedef float  f32x4  __attribute__((ext_vector_type(4)));
typedef short  bf16x8 __attribute__((ext_vector_type(8)));

__device__ __forceinline__ unsigned short f2bf(float f) {
    union { float f; unsigned u; } v; v.f = f;
    unsigned u = v.u;
    unsigned r = (u + 0x7FFFu + ((u >> 16) & 1u)) >> 16;   // RNE
    return (unsigned short)r;
}

// packed f32x2 -> bf16x2 (RNE), lo -> low 16 bits
__device__ __forceinline__ unsigned pk2bf(float lo, float hi) {
    unsigned r;
    asm("v_cvt_pk_bf16_f32 %0, %1, %2" : "=v"(r) : "v"(lo), "v"(hi));
    return r;
}

__device__ __forceinline__ float f4get(const float4& v, int i) {
    return i == 0 ? v.x : i == 1 ? v.y : i == 2 ? v.z : v.w;
}

#define SBAR() __builtin_amdgcn_sched_barrier(0)

// LDS-only barrier: ds-writes visible, NO vmcnt(0) drain (keeps prefetch loads in flight)
__device__ __forceinline__ void barrier_lds() {
    asm volatile("s_waitcnt lgkmcnt(0)" ::: "memory");
    SBAR();
    __builtin_amdgcn_s_barrier();
    SBAR();
}

// ---------------- router: 4 tokens/block; logits -> top2 weight; x -> bf16 --
__global__ __launch_bounds__(256) void router_kernel(
    const float* __restrict__ x, const float* __restrict__ Wr,
    int* counts, int* expert_of, int* slot_of, float* wt_of,
    unsigned short* __restrict__ Xbf) {
    int lane = threadIdx.x & 63;
    int t = blockIdx.x * 4 + (threadIdx.x >> 6);
    const float* xr = x + (size_t)t * DMODEL;
    unsigned short* xb = Xbf + (size_t)t * DMODEL;
    float p[NEXP];
#pragma unroll
    for (int e = 0; e < NEXP; ++e) p[e] = 0.f;
#pragma unroll
    for (int q = 0; q < 4; ++q) {
        int d = q * 256 + lane * 4;
        float4 v = *(const float4*)(xr + d);
        ushort4 b;
        b.x = f2bf(v.x); b.y = f2bf(v.y); b.z = f2bf(v.z); b.w = f2bf(v.w);
        *(ushort4*)(xb + d) = b;
#pragma unroll
        for (int j = 0; j < 4; ++j) {
            float xv = f4get(v, j);
            const float* wr = Wr + (size_t)(d + j) * NEXP;
#pragma unroll
            for (int e = 0; e < NEXP; ++e) p[e] += xv * wr[e];
        }
    }
#pragma unroll
    for (int e = 0; e < NEXP; ++e) {
        for (int off = 32; off > 0; off >>= 1)
            p[e] += __shfl_down(p[e], off, 64);
    }
    if (lane == 0) {
        int i0 = 0; float v0 = p[0];
        for (int e = 1; e < NEXP; ++e) if (p[e] > v0) { v0 = p[e]; i0 = e; }
        float v1 = -INFINITY;
        for (int e = 0; e < NEXP; ++e) if (e != i0 && p[e] > v1) v1 = p[e];
        float w = 1.f / (1.f + expf(v1 - v0));
        expert_of[t] = i0;
        wt_of[t] = w;
        slot_of[t] = atomicAdd(&counts[i0], 1);
    }
}

// ---------------- scan + tile list + scatter -------------------------------
__global__ void scan_scatter_kernel(const int* counts, int* offsets,
                                    int* tileE, int* tileM, int* tileCount,
                                    const int* expert_of, const int* slot_of,
                                    int* perm) {
    __shared__ int soff[NEXP];
    if (threadIdx.x == 0) {
        int run = 0, tc = 0;
        for (int e = 0; e < NEXP; ++e) {
            offsets[e] = run; soff[e] = run;
            for (int m0 = 0; m0 < counts[e]; m0 += 128) {
                tileE[tc] = e; tileM[tc] = m0; ++tc;
            }
            run += counts[e];
        }
        *tileCount = tc;
    }
    __syncthreads();
    for (int t = threadIdx.x; t < T_TOKENS; t += blockDim.x)
        perm[soff[expert_of[t]] + slot_of[t]] = t;
}

// ===========================================================================
// GEMM1: H = GELU(Xbf[perm] @ W1). 512 thr, wave-tile 32x64, reg-staged A+B,
// fused f32->bf16 B convert, raw-barrier pipeline (no vmcnt drain).
// ===========================================================================
__global__ __launch_bounds__(512, 4) void gemm1_kernel(
    const unsigned short* __restrict__ Xbf, const float* __restrict__ W1,
    const int* __restrict__ counts, const int* __restrict__ offsets,
    const int* __restrict__ perm, const int* __restrict__ tileE,
    const int* __restrict__ tileM, const int* __restrict__ tileCount,
    unsigned short* __restrict__ H) {

    const int NT = HID / 128;                 // 32
    int tile = blockIdx.x / NT;
    int nt   = blockIdx.x % NT;
    if (tile >= *tileCount) return;
    int e = tileE[tile], m0 = tileM[tile];
    int rows_e = counts[e], base = offsets[e];
    int n0 = nt * 128;

    __shared__ unsigned short Alds[2][128 * 64];
    __shared__ unsigned short Blds[2][128 * 64];

    int tid  = threadIdx.x;
    int lane = tid & 63;
    int wid  = tid >> 6;                      // 0..7
    int wm = wid >> 1, wn = wid & 1;          // 4 m-strips x 2 n-halves
    const int swz = (lane & 7) << 4;

    // ---- A staging: 2 x 16B per thread, swizzled ds_write ----
    const unsigned short* ag[2];
    int awr[2];
#pragma unroll
    for (int p = 0; p < 2; ++p) {
        int idx = p * 512 + tid;
        int row = idx >> 3, seg = idx & 7;
        int r = m0 + row;
        int tok = perm[base + (r < rows_e ? r : rows_e - 1)];
        ag[p]  = Xbf + (size_t)tok * DMODEL + seg * 8;
        awr[p] = row * 128 + ((seg * 16) ^ ((row & 7) << 4));
    }
    // ---- B staging: thread owns [4k x 4n] f32 ----
    const int kq4 = (tid & 15) * 4;
    const int n4  = ((tid >> 4) & 31) * 4;
    const float* bsrc = W1 + ((size_t)e * DMODEL + kq4) * HID + n0 + n4;
    int bwr[4];
#pragma unroll
    for (int j = 0; j < 4; ++j) {
        int n = n4 + j;
        bwr[j] = n * 128 + ((kq4 * 2) ^ ((n & 7) << 4));
    }

    f32x4 acc[2][4];
#pragma unroll
    for (int i = 0; i < 2; ++i)
#pragma unroll
        for (int j = 0; j < 4; ++j) acc[i][j] = (f32x4){0.f, 0.f, 0.f, 0.f};

    float4 areg[2]; float4 breg[4];

#define G_LOADA(kt) do {                                                      \
    areg[0] = *(const float4*)(ag[0] + (kt) * 64);                            \
    areg[1] = *(const float4*)(ag[1] + (kt) * 64);                            \
} while (0)
#define G_LOADB(kt, STRIDE) do {                                              \
    _Pragma("unroll")                                                         \
    for (int r_ = 0; r_ < 4; ++r_)                                            \
        breg[r_] = *(const float4*)(bsrc + ((size_t)(kt) * 64 + r_) * (STRIDE)); \
} while (0)
#define G_STAGE(BUF) do {                                                     \
    *(float4*)((char*)Alds[BUF] + awr[0]) = areg[0];                          \
    *(float4*)((char*)Alds[BUF] + awr[1]) = areg[1];                          \
    _Pragma("unroll")                                                         \
    for (int j_ = 0; j_ < 4; ++j_) {                                          \
        unsigned lo_ = pk2bf(f4get(breg[0], j_), f4get(breg[1], j_));         \
        unsigned hi_ = pk2bf(f4get(breg[2], j_), f4get(breg[3], j_));         \
        unsigned long long w_ = ((unsigned long long)hi_ << 32) | lo_;        \
        *(unsigned long long*)((char*)Blds[BUF] + bwr[j_]) = w_;              \
    }                                                                         \
} while (0)
#define G_COMPUTE(BUF) do {                                                   \
    const char* ab_ = (const char*)Alds[BUF];                                 \
    const char* bb_ = (const char*)Blds[BUF];                                 \
    _Pragma("unroll")                                                         \
    for (int ks_ = 0; ks_ < 2; ++ks_) {                                       \
        int kb_ = (ks_ * 32 + ((lane >> 4) * 8)) * 2;                         \
        bf16x8 af_[2], bf_[4];                                                \
        _Pragma("unroll")                                                     \
        for (int i_ = 0; i_ < 2; ++i_) {                                      \
            int m_ = wm * 32 + i_ * 16 + (lane & 15);                         \
            af_[i_] = *(const bf16x8*)(ab_ + m_ * 128 + (kb_ ^ swz));         \
        }                                                                     \
        _Pragma("unroll")                                                     \
        for (int j_ = 0; j_ < 4; ++j_) {                                      \
            int n_ = wn * 64 + j_ * 16 + (lane & 15);                         \
            bf_[j_] = *(const bf16x8*)(bb_ + n_ * 128 + (kb_ ^ swz));         \
        }                                                                     \
        _Pragma("unroll")                                                     \
        for (int i_ = 0; i_ < 2; ++i_)                                        \
            _Pragma("unroll")                                                 \
            for (int j_ = 0; j_ < 4; ++j_)                                    \
                acc[i_][j_] = __builtin_amdgcn_mfma_f32_16x16x32_bf16(af_[i_], bf_[j_], acc[i_][j_], 0, 0, 0); \
    }                                                                         \
} while (0)

    // prologue: tile 0 staged; tile 1 prefetched into regs
    G_LOADA(0); G_LOADB(0, HID);
    G_STAGE(0);
    G_LOADA(1); G_LOADB(1, HID);
    barrier_lds();

#pragma unroll 1
    for (int t = 0; t < 15; ++t) {
        int cur = t & 1, nxt = cur ^ 1;
        G_STAGE(nxt);                         // stage tile t+1 (regs loaded last iter)
        G_COMPUTE(cur);                       // compute tile t (interleaved by scheduler)
        if (t < 14) { G_LOADA(t + 2); G_LOADB(t + 2, HID); }
        barrier_lds();
    }
    G_COMPUTE(1);                             // tile 15

    int quad = lane >> 4, col = lane & 15;
#pragma unroll
    for (int i = 0; i < 2; ++i)
#pragma unroll
        for (int j = 0; j < 4; ++j)
#pragma unroll
            for (int r = 0; r < 4; ++r) {
                int ml = wm * 32 + i * 16 + quad * 4 + r;
                if (m0 + ml < rows_e) {
                    int n = n0 + wn * 64 + j * 16 + col;
                    float v = acc[i][j][r];
                    float g = 0.5f * v * (1.0f + erff(v * 0.70710678118654752f));
                    H[(size_t)(base + m0 + ml) * HID + n] = f2bf(g);
                }
            }
}

// ===========================================================================
// GEMM2 (split-K=4): out += wt * (H @ W2). Same structure.
// ===========================================================================
__global__ __launch_bounds__(512, 4) void gemm2_kernel(
    const unsigned short* __restrict__ H, const float* __restrict__ W2,
    const int* __restrict__ counts, const int* __restrict__ offsets,
    const int* __restrict__ perm, const float* __restrict__ wt_of,
    const int* __restrict__ tileE, const int* __restrict__ tileM,
    const int* __restrict__ tileCount, float* __restrict__ out) {

    const int NT = DMODEL / 128;              // 8
    int tile = blockIdx.x / (NT * 4);
    int rem  = blockIdx.x % (NT * 4);
    int nt   = rem >> 2;
    int sk   = rem & 3;
    if (tile >= *tileCount) return;
    int e = tileE[tile], m0 = tileM[tile];
    int rows_e = counts[e], base = offsets[e];
    int n0 = nt * 128;
    int kbeg = sk * (HID / 4);                // 1024-wide K slice

    __shared__ unsigned short Alds[2][128 * 64];
    __shared__ unsigned short Blds[2][128 * 64];
    __shared__ int   rowTok[128];
    __shared__ float rowW[128];

    int tid  = threadIdx.x;
    int lane = tid & 63;
    int wid  = tid >> 6;
    int wm = wid >> 1, wn = wid & 1;
    const int swz = (lane & 7) << 4;

    if (tid < 128) {
        int r = m0 + tid;
        if (r < rows_e) {
            int tok = perm[base + r];
            rowTok[tid] = tok;
            rowW[tid]   = wt_of[tok];
        } else { rowTok[tid] = 0; rowW[tid] = 0.f; }
    }

    const unsigned short* ag[2];
    int awr[2];
#pragma unroll
    for (int p = 0; p < 2; ++p) {
        int idx = p * 512 + tid;
        int row = idx >> 3, seg = idx & 7;
        int hr = base + m0 + row;
        if (hr > T_TOKENS - 1) hr = T_TOKENS - 1;
        ag[p]  = H + (size_t)hr * HID + kbeg + seg * 8;
        awr[p] = row * 128 + ((seg * 16) ^ ((row & 7) << 4));
    }
    const int kq4 = (tid & 15) * 4;
    const int n4  = ((tid >> 4) & 31) * 4;
    const float* bsrc = W2 + ((size_t)e * HID + kbeg + kq4) * DMODEL + n0 + n4;
    int bwr[4];
#pragma unroll
    for (int j = 0; j < 4; ++j) {
        int n = n4 + j;
        bwr[j] = n * 128 + ((kq4 * 2) ^ ((n & 7) << 4));
    }

    f32x4 acc[2][4];
#pragma unroll
    for (int i = 0; i < 2; ++i)
#pragma unroll
        for (int j = 0; j < 4; ++j) acc[i][j] = (f32x4){0.f, 0.f, 0.f, 0.f};

    float4 areg[2]; float4 breg[4];

    G_LOADA(0); G_LOADB(0, DMODEL);
    G_STAGE(0);
    G_LOADA(1); G_LOADB(1, DMODEL);
    barrier_lds();

#pragma unroll 1
    for (int t = 0; t < 15; ++t) {
        int cur = t & 1, nxt = cur ^ 1;
        G_STAGE(nxt);
        G_COMPUTE(cur);
        if (t < 14) { G_LOADA(t + 2); G_LOADB(t + 2, DMODEL); }
        barrier_lds();
    }
    G_COMPUTE(1);

    int quad = lane >> 4, col = lane & 15;
#pragma unroll
    for (int i = 0; i < 2; ++i)
#pragma unroll
        for (int j = 0; j < 4; ++j)
#pragma unroll
            for (int r = 0; r < 4; ++r) {
                int ml = wm * 32 + i * 16 + quad * 4 + r;
                if (m0 + ml < rows_e) {
                    int tok = rowTok[ml];
                    float w = rowW[ml];
                    int n = n0 + wn * 64 + j * 16 + col;
                    atomicAdd(&out[(size_t)tok * DMODEL + n], w * acc[i][j][r]);
                }
            }
}

extern "C" void kernel_launch(void* const* d_in, const int* in_sizes, int n_in,
                              void* d_out, int out_size, void* d_ws, size_t ws_size,
                              hipStream_t stream) {
    const float* x  = (const float*)d_in[0];
    const float* Wr = (const float*)d_in[1];
    const float* W1 = (const float*)d_in[2];
    const float* W2 = (const float*)d_in[3];
    float* out = (float*)d_out;

    char* ws = (char*)d_ws;
    int*   counts    = (int*)(ws);
    int*   offsets   = (int*)(ws + 64);
    int*   tileCount = (int*)(ws + 128);
    int*   tileE     = (int*)(ws + 256);
    int*   tileM     = (int*)(ws + 256 + 4 * MAX_TILES);
    int*   expert_of = (int*)(ws + 1024);
    int*   slot_of   = (int*)(ws + 1024 + 8192);
    float* wt_of     = (float*)(ws + 1024 + 16384);
    int*   perm      = (int*)(ws + 1024 + 24576);
    size_t off = 65536;
    unsigned short* Xbf  = (unsigned short*)(ws + off); off += (size_t)T_TOKENS * DMODEL * 2;  // 4 MB
    unsigned short* Hbuf = (unsigned short*)(ws + off);                                        // 16 MB

    hipMemsetAsync(counts, 0, 64, stream);
    hipMemsetAsync(out, 0, (size_t)T_TOKENS * DMODEL * sizeof(float), stream);

    router_kernel<<<T_TOKENS / 4, 256, 0, stream>>>(x, Wr, counts, expert_of, slot_of, wt_of, Xbf);
    scan_scatter_kernel<<<1, 256, 0, stream>>>(counts, offsets, tileE, tileM, tileCount,
                                               expert_of, slot_of, perm);

    gemm1_kernel<<<MAX_TILES * (HID / 128), 512, 0, stream>>>(
        Xbf, W1, counts, offsets, perm, tileE, tileM, tileCount, Hbuf);
    gemm2_kernel<<<MAX_TILES * (DMODEL / 128) * 4, 512, 0, stream>>>(
        Hbuf, W2, counts, offsets, perm, wt_of, tileE, tileM, tileCount, out);
}